// Round 5
// baseline (63.625 us; speedup 1.0000x reference)
//
#include <hip/hip_runtime.h>

#define N_CELLS   16384
#define N_CLASSES 64
#define BATCH     64
#define CPB       128   // cells per block (one batch row segment)

typedef float f32x4 __attribute__((ext_vector_type(4)));
typedef float f32x2 __attribute__((ext_vector_type(2)));

// log2(e) * 4/3 : exp(-(4/3)x) == exp2(-1.9235933878x)
#define K_EXP 1.9235933878f

__device__ __forceinline__ float agm_act(float s) {
    // 1.7159*tanh((2/3)s) = 3.4318/(1+exp2(-K*|s|)) - 1.7159, sign-restored
    float e = __builtin_amdgcn_exp2f(-K_EXP * fabsf(s));
    float r = __builtin_amdgcn_rcpf(1.0f + e);
    return copysignf(fmaf(3.4318f, r, -1.7159f), s);
}

__global__ __launch_bounds__(256) void mnl_kernel(
    const float* __restrict__ x,     // (B, N)
    const float* __restrict__ w,     // (N, C, 3)
    const float* __restrict__ bias,  // (N, C)
    float* __restrict__ out)         // (B, N, C)
{
    const int bid   = blockIdx.x;
    const int b     = bid >> 7;          // batch row
    const int chunk = bid & 127;         // cell chunk within row
    const int i0    = chunk * CPB;
    const int t     = threadIdx.x;

    const float* __restrict__ xb = x + (size_t)b * N_CELLS;
    float* __restrict__ ob = out + (size_t)b * N_CELLS * N_CLASSES
                                 + (size_t)i0 * N_CLASSES;

    // 8 iterations x 256 threads x float4 = 32KB contiguous per block
    #pragma unroll 4
    for (int it = 0; it < 8; ++it) {
        const int slot = it * 256 + t;       // 0..2047
        const int cell = slot >> 4;          // 0..127
        const int quad = slot & 15;          // class quad
        const int i    = i0 + cell;

        const int il = (i == 0)           ? N_CELLS - 1 : i - 1;
        const int ir = (i == N_CELLS - 1) ? 0           : i + 1;

        const float xl = xb[il];
        const float xc = xb[i];
        const float xr = xb[ir];

        const float4* wv = reinterpret_cast<const float4*>(
            w + (size_t)i * (N_CLASSES * 3) + (size_t)quad * 12);
        const float4 v0 = wv[0], v1 = wv[1], v2 = wv[2];
        const float4 bi = *reinterpret_cast<const float4*>(
            bias + (size_t)i * N_CLASSES + quad * 4);

        // class j: w0=wr[3j], w1=wr[3j+1], w2=wr[3j+2]
        f32x4 o;
        o.x = agm_act(fmaf(xl, v0.x, fmaf(xc, v0.y, fmaf(xr, v0.z, bi.x))));
        o.y = agm_act(fmaf(xl, v0.w, fmaf(xc, v1.x, fmaf(xr, v1.y, bi.y))));
        o.z = agm_act(fmaf(xl, v1.z, fmaf(xc, v1.w, fmaf(xr, v2.x, bi.z))));
        o.w = agm_act(fmaf(xl, v2.y, fmaf(xc, v2.z, fmaf(xr, v2.w, bi.w))));

        f32x4* op = reinterpret_cast<f32x4*>(ob + (size_t)slot * 4);
        __builtin_nontemporal_store(o, op);
    }
}

extern "C" void kernel_launch(void* const* d_in, const int* in_sizes, int n_in,
                              void* d_out, int out_size, void* d_ws, size_t ws_size,
                              hipStream_t stream) {
    const float* x    = (const float*)d_in[0];  // (64, 16384, 1)
    const float* w    = (const float*)d_in[1];  // (16384, 64, 3)
    const float* bias = (const float*)d_in[2];  // (16384, 64)
    float* out = (float*)d_out;                 // (64, 16384, 64)

    dim3 grid(BATCH * (N_CELLS / CPB));   // 64 * 128 = 8192
    dim3 block(256);
    mnl_kernel<<<grid, block, 0, stream>>>(x, w, bias, out);
}